// Round 6
// baseline (4160.168 us; speedup 1.0000x reference)
//
#include <hip/hip_runtime.h>
#include <math.h>

typedef short bf16x8 __attribute__((ext_vector_type(8)));
typedef float f32x4  __attribute__((ext_vector_type(4)));
typedef unsigned short u16;

// Problem constants (B=4096, T=100, F=13, H=100)
#define B_  4096
#define T_  100
#define F_  13
#define NB  128    // blocks (L2-proven config: weight set stays L2-resident)
#define MR  32     // rows per block (amortizes the fixed 630KB/step B stream)
#define S0  136    // A0 row stride u16: [0..100)=h0, [100..113)=x, [113..136)=0
#define S1  232    // A1 row stride u16: [0..100)=h0n, [100..200)=h1, [200..232)=0

// ws layout (bytes), total 651,264 (same as round 3)
#define O_HIST   0u
#define O_ROWMAP 512u
#define O_BIAS0  16896u
#define O_BIAS1  18688u
#define O_B0     20480u    // 229376 B
#define O_B1     249856u   // 401408 B -> 651264

// B-fragment layout (u16 index) — ROUND-3 PROVEN (L2-resident):
//   idx = (((kt*4+g)*7 + ct)*2 + pass)*512 + lane*8 + j
// lane elem j = W_pass[k = kt*32 + (lane>>4)*8 + j][col = g*100 + ct*16 + (lane&15)]

__device__ __forceinline__ float sigmoid_f(float v) {
    return 1.0f / (1.0f + __expf(-v));
}
__device__ __forceinline__ float tanh_f(float v) {
    float e = __expf(2.0f * v);
    return 1.0f - 2.0f / (e + 1.0f);
}
__device__ __forceinline__ void split_bf16(float v, u16& hi, u16& lo) {
    unsigned u = __float_as_uint(v);
    hi = (u16)(u >> 16);
    float rem = v - __uint_as_float(u & 0xFFFF0000u);
    unsigned r = __float_as_uint(rem);
    unsigned rnd = r + 0x7FFFu + ((r >> 16) & 1u);
    lo = (u16)(rnd >> 16);
}
__device__ __forceinline__ float bf16_to_f(u16 b) {
    return __uint_as_float(((unsigned)b) << 16);
}

// integral-constant tag (namespace scope — local structs can't host static members)
template <int S> struct IC { static constexpr int value = S; };

// ---------------- prep kernels (round-3 proven, verbatim) ----------------
__global__ void k_hist(const int* __restrict__ len, int* __restrict__ hist) {
    int b = blockIdx.x * blockDim.x + threadIdx.x;
    if (b < B_) atomicAdd(&hist[len[b]], 1);
}
__global__ void k_scan(int* __restrict__ hist) {
    if (threadIdx.x == 0 && blockIdx.x == 0) {
        int acc = 0;
        for (int l = 0; l <= 100; ++l) { int c = hist[l]; hist[l] = acc; acc += c; }
    }
}
__global__ void k_scatter(const int* __restrict__ len, int* __restrict__ hist,
                          int* __restrict__ rowmap) {
    int b = blockIdx.x * blockDim.x + threadIdx.x;
    if (b < B_) {
        int pos = atomicAdd(&hist[len[b]], 1);
        rowmap[pos] = b;
    }
}
__global__ void k_prep_bias(const float* __restrict__ bih0, const float* __restrict__ bhh0,
                            const float* __restrict__ bih1, const float* __restrict__ bhh1,
                            float* __restrict__ bias0, float* __restrict__ bias1) {
    int idx = blockIdx.x * blockDim.x + threadIdx.x;
    if (idx < 448) {
        int g = idx / 112, cell = idx % 112;
        float v0 = 0.f, v1 = 0.f;
        if (cell < 100) {
            int row = g * 100 + cell;
            v0 = bih0[row] + bhh0[row];
            v1 = bih1[row] + bhh1[row];
        }
        bias0[idx] = v0; bias1[idx] = v1;
    }
}
__global__ void k_prep_b(const float* __restrict__ Wih0, const float* __restrict__ Whh0,
                         const float* __restrict__ Wih1, const float* __restrict__ Whh1,
                         u16* __restrict__ B0, u16* __restrict__ B1) {
    const int PER_KT = 4 * 7 * 2 * 512;  // 28672 u16 per K-tile
    int idx = blockIdx.x * blockDim.x + threadIdx.x;
    if (idx >= 7 * PER_KT) return;
    int kt = idx / PER_KT;
    int s  = idx % PER_KT;
    int g  = s / 7168;
    int s2 = s % 7168;
    int ct = s2 / 1024;
    int s3 = s2 % 1024;
    int pass = s3 / 512;
    int e  = s3 % 512;
    int lane = e >> 3, j = e & 7;
    int n = lane & 15, q = lane >> 4;
    int k = kt * 32 + q * 8 + j;
    int cell = ct * 16 + n;
    u16 hi, lo;
    {   // layer 1
        float w = 0.f;
        if (cell < 100) {
            int row = g * 100 + cell;
            if (k < 100)      w = Wih1[row * 100 + k];
            else if (k < 200) w = Whh1[row * 100 + (k - 100)];
        }
        split_bf16(w, hi, lo);
        B1[idx] = pass ? lo : hi;
    }
    if (kt < 4) {  // layer 0
        float w = 0.f;
        if (cell < 100) {
            int row = g * 100 + cell;
            if (k < 100)      w = Whh0[row * 100 + k];
            else if (k < 113) w = Wih0[row * 13 + (k - 100)];
        }
        split_bf16(w, hi, lo);
        B0[idx] = pass ? lo : hi;
    }
}

// ---------------- fragment pipeline helpers ----------------
struct FragB { bf16x8 h[4]; bf16x8 l[4]; };

// bp = B + ct*1024 + lane*8 ; chunk kt, gate g at +(kt*4+g)*7168 (+512 for lo)
__device__ __forceinline__ void loadB(const u16* __restrict__ bp, int kt, FragB& f) {
#pragma unroll
    for (int g = 0; g < 4; ++g) {
        const u16* p = bp + (size_t)(kt * 4 + g) * 7168;
        f.h[g] = *(const bf16x8*)(p);
        f.l[g] = *(const bf16x8*)(p + 512);
    }
}

__device__ __forceinline__ void compChunk(const FragB& f,
                                          const u16* __restrict__ aH,
                                          const u16* __restrict__ aL,
                                          int kt, int stride, f32x4 (&P)[2][4]) {
#pragma unroll
    for (int mt = 0; mt < 2; ++mt) {
        bf16x8 ah = *(const bf16x8*)(aH + mt * 16 * stride + kt * 32);
        bf16x8 al = *(const bf16x8*)(aL + mt * 16 * stride + kt * 32);
#pragma unroll
        for (int g = 0; g < 4; ++g) {
            P[mt][g] = __builtin_amdgcn_mfma_f32_16x16x32_bf16(ah, f.h[g], P[mt][g], 0, 0, 0);
            P[mt][g] = __builtin_amdgcn_mfma_f32_16x16x32_bf16(al, f.h[g], P[mt][g], 0, 0, 0);
            P[mt][g] = __builtin_amdgcn_mfma_f32_16x16x32_bf16(ah, f.l[g], P[mt][g], 0, 0, 0);
        }
    }
}

// Pipelined GEMM phase: chunks 0..KT-1; loads issued 2 ahead; last two issues
// prefetch the NEXT phase's chunks 0,1 (they drain at the following barrier).
// S3 = rotation start slot (compile-time); chunk c lives in F[(S3+c)%3].
template <int KT, int S3>
__device__ __forceinline__ void gemmPhase(const u16* __restrict__ bp,
                                          const u16* __restrict__ bpNext,
                                          const u16* __restrict__ aH,
                                          const u16* __restrict__ aL,
                                          int stride, FragB (&F)[3], f32x4 (&P)[2][4]) {
#pragma unroll
    for (int kt = 0; kt < KT; ++kt) {
        if (kt + 2 < KT) loadB(bp,     kt + 2,      F[(S3 + kt + 2) % 3]);
        else             loadB(bpNext, kt + 2 - KT, F[(S3 + kt + 2) % 3]);
        compChunk(F[(S3 + kt) % 3], aH, aL, kt, stride, P);
    }
}

// ---------------- main persistent MFMA LSTM ----------------
// 128 blocks x 32 rows, 8 waves: waves 0..6 = 16-cell column tiles (all 4
// gates, both 16-row M-tiles), wave 7 = x prefetcher. 3 barriers/step.
__global__ __launch_bounds__(512, 2) void k_lstm(
    const float* __restrict__ x, const int* __restrict__ lengths,
    const int* __restrict__ rowmap,
    const u16* __restrict__ B0, const u16* __restrict__ B1,
    const float* __restrict__ bias0, const float* __restrict__ bias1,
    const float* __restrict__ Wfc, const float* __restrict__ bfc,
    float* __restrict__ out)
{
    __shared__ __align__(16) u16 Ah0[2][MR * S0];   // double-buffered h0|x
    __shared__ __align__(16) u16 Al0[2][MR * S0];
    __shared__ __align__(16) u16 Ah1[MR * S1];      // single-buffered h0n|h1
    __shared__ __align__(16) u16 Al1[MR * S1];
    __shared__ int sRow[MR], sLen[MR], sTmax;

    const int tid = threadIdx.x;
    const int wv = tid >> 6, lane = tid & 63;

    if (tid < MR) {
        int r = rowmap[blockIdx.x * MR + tid];
        sRow[tid] = r; sLen[tid] = lengths[r];
    }
    if (tid == 0) {   // same wave as the writes above -> in-order LDS
        int m = 0;
        for (int i = 0; i < MR; ++i) m = max(m, sLen[i]);
        sTmax = m;
    }
    {
        unsigned* p0 = (unsigned*)&Ah0[0][0]; unsigned* p1 = (unsigned*)&Al0[0][0];
        unsigned* p2 = (unsigned*)&Ah1[0];    unsigned* p3 = (unsigned*)&Al1[0];
        for (int i = tid; i < MR * S0; i += 512) { p0[i] = 0; p1[i] = 0; }  // both parities
        for (int i = tid; i < (MR * S1) / 2; i += 512) { p2[i] = 0; p3[i] = 0; }
    }
    __syncthreads();
    const int Tmax = sTmax;

    const int n = lane & 15, q = lane >> 4;
    const int ct = wv;
    const int cell = ct * 16 + n;
    const bool cw = (wv < 7) && (cell < 100);

    float b0v[4], b1v[4], c0[8], c1[8];
    int   lenR[8];
    int   offA0 = 0, offA1 = 0;
    const u16* b0p = B0; const u16* b1p = B1;
    FragB F[3];

    // x-wave state (32 rows x 13 feats = 416 slots, 7 per lane)
    float xv[7]; int xok[7]; size_t xg[7]; int xa[7];

    if (wv < 7) {
#pragma unroll
        for (int g = 0; g < 4; ++g) {
            b0v[g] = bias0[g * 112 + cell];
            b1v[g] = bias1[g * 112 + cell];
        }
#pragma unroll
        for (int mt = 0; mt < 2; ++mt)
#pragma unroll
            for (int r = 0; r < 4; ++r) {
                int i = mt * 4 + r;
                lenR[i] = sLen[mt * 16 + q * 4 + r];
                c0[i] = 0.f; c1[i] = 0.f;
            }
        offA0 = n * S0 + q * 8;
        offA1 = n * S1 + q * 8;
        b0p = B0 + ct * 1024 + lane * 8;
        b1p = B1 + ct * 1024 + lane * 8;
        loadB(b0p, 0, F[0]);     // L0 chunk0 -> slot 0
        loadB(b0p, 1, F[1]);     // L0 chunk1 -> slot 1
    } else {
#pragma unroll
        for (int i = 0; i < 7; ++i) {
            int e = i * 64 + lane;
            xok[i] = (e < MR * F_);
            int r = xok[i] ? (e / F_) : 0;
            int f = xok[i] ? (e - F_ * r) : 0;
            xg[i] = (size_t)sRow[r] * (T_ * F_) + f;
            xa[i] = r * S0 + 100 + f;
            if (xok[i]) {        // x(0) -> parity-0 buffer (published by first barrier)
                u16 hi, lo; split_bf16(x[xg[i]], hi, lo);
                Ah0[0][xa[i]] = hi; Al0[0][xa[i]] = lo;
            }
        }
    }

    int t = 0;
    auto stepf = [&](auto SC) {
        constexpr int S  = SC.value;
        constexpr int SA = (2 * S) % 3;        // L0 chunk0 slot this step
        constexpr int SB = (2 * S + 1) % 3;    // L1 chunk0 slot this step
        const int rd = t & 1, wr = rd ^ 1;

        __syncthreads();   // B1: x(t)+h0(t-1) in A0[rd]; prior h1 writes done
        f32x4 P[2][4];
        if (wv < 7) {
#pragma unroll
            for (int mt = 0; mt < 2; ++mt)
#pragma unroll
                for (int g = 0; g < 4; ++g)
                    P[mt][g] = (f32x4){b0v[g], b0v[g], b0v[g], b0v[g]};
            gemmPhase<4, SA>(b0p, b1p, &Ah0[rd][offA0], &Al0[rd][offA0], S0, F, P);
            // pointwise layer 0; h0(t)->A0[wr], h0n(t)->A1[:100]
#pragma unroll
            for (int mt = 0; mt < 2; ++mt)
#pragma unroll
                for (int r = 0; r < 4; ++r) {
                    int i = mt * 4 + r;
                    float zi = P[mt][0][r], zf = P[mt][1][r];
                    float zg = P[mt][2][r], zo = P[mt][3][r];
                    float cn = sigmoid_f(zf) * c0[i] + sigmoid_f(zi) * tanh_f(zg);
                    float hn = sigmoid_f(zo) * tanh_f(cn);
                    if (t < lenR[i]) {
                        c0[i] = cn;
                        if (cw) {
                            int m = mt * 16 + q * 4 + r;
                            u16 hi, lo; split_bf16(hn, hi, lo);
                            Ah0[wr][m * S0 + cell] = hi; Al0[wr][m * S0 + cell] = lo;
                            Ah1[m * S1 + cell]     = hi; Al1[m * S1 + cell]     = lo;
                        }
                    }
                }
        } else {
            if (t + 1 < Tmax) {
#pragma unroll
                for (int i = 0; i < 7; ++i)
                    if (xok[i]) xv[i] = x[xg[i] + (size_t)(t + 1) * F_];
            }
        }

        __syncthreads();   // B2: h0n(t) visible; L1 chunks 0,1 drained into regs
        if (wv < 7) {
#pragma unroll
            for (int mt = 0; mt < 2; ++mt)
#pragma unroll
                for (int g = 0; g < 4; ++g)
                    P[mt][g] = (f32x4){b1v[g], b1v[g], b1v[g], b1v[g]};
            gemmPhase<7, SB>(b1p, b0p, &Ah1[offA1], &Al1[offA1], S1, F, P);
        } else {
            if (t + 1 < Tmax) {   // x(t+1) -> A0[wr] (nobody reads wr this step)
#pragma unroll
                for (int i = 0; i < 7; ++i) if (xok[i]) {
                    u16 hi, lo; split_bf16(xv[i], hi, lo);
                    Ah0[wr][xa[i]] = hi; Al0[wr][xa[i]] = lo;
                }
            }
        }

        __syncthreads();   // B3: all A1 fragment reads done -> safe to write h1
        if (wv < 7) {
#pragma unroll
            for (int mt = 0; mt < 2; ++mt)
#pragma unroll
                for (int r = 0; r < 4; ++r) {
                    int i = mt * 4 + r;
                    float zi = P[mt][0][r], zf = P[mt][1][r];
                    float zg = P[mt][2][r], zo = P[mt][3][r];
                    float cn = sigmoid_f(zf) * c1[i] + sigmoid_f(zi) * tanh_f(zg);
                    float hn = sigmoid_f(zo) * tanh_f(cn);
                    if (t < lenR[i]) {
                        c1[i] = cn;
                        if (cw) {
                            int m = mt * 16 + q * 4 + r;
                            u16 hi, lo; split_bf16(hn, hi, lo);
                            Ah1[m * S1 + 100 + cell] = hi;
                            Al1[m * S1 + 100 + cell] = lo;
                        }
                    }
                }
        }
    };

    for (t = 0; t < Tmax; ++t) {
        switch (t % 3) {
            case 0: stepf(IC<0>{}); break;
            case 1: stepf(IC<1>{}); break;
            default: stepf(IC<2>{}); break;
        }
    }
    __syncthreads();

    // out[b] = W_fc . h1(len-1) + b_fc  (A1 single-buffered, frozen at len-1)
    if (tid < MR) {
        float s = bfc[0];
        for (int j = 0; j < 100; ++j)
            s = fmaf(Wfc[j], bf16_to_f(Ah1[tid * S1 + 100 + j]) +
                             bf16_to_f(Al1[tid * S1 + 100 + j]), s);
        out[sRow[tid]] = s;
    }
}

// ---------------- launch ----------------
extern "C" void kernel_launch(void* const* d_in, const int* in_sizes, int n_in,
                              void* d_out, int out_size, void* d_ws, size_t ws_size,
                              hipStream_t stream) {
    const float* x    = (const float*)d_in[0];
    const int*   len  = (const int*)d_in[1];
    const float* Wih0 = (const float*)d_in[2];
    const float* Whh0 = (const float*)d_in[3];
    const float* bih0 = (const float*)d_in[4];
    const float* bhh0 = (const float*)d_in[5];
    const float* Wih1 = (const float*)d_in[6];
    const float* Whh1 = (const float*)d_in[7];
    const float* bih1 = (const float*)d_in[8];
    const float* bhh1 = (const float*)d_in[9];
    const float* Wfc  = (const float*)d_in[10];
    const float* bfc  = (const float*)d_in[11];
    float* out = (float*)d_out;

    char* ws = (char*)d_ws;   // uses 651,264 bytes
    int*   hist   = (int*)(ws + O_HIST);
    int*   rowmap = (int*)(ws + O_ROWMAP);
    float* bias0  = (float*)(ws + O_BIAS0);
    float* bias1  = (float*)(ws + O_BIAS1);
    u16*   B0     = (u16*)(ws + O_B0);
    u16*   B1     = (u16*)(ws + O_B1);

    (void)hipMemsetAsync(hist, 0, 512, stream);
    k_hist<<<16, 256, 0, stream>>>(len, hist);
    k_scan<<<1, 64, 0, stream>>>(hist);
    k_scatter<<<16, 256, 0, stream>>>(len, hist, rowmap);
    k_prep_bias<<<2, 256, 0, stream>>>(bih0, bhh0, bih1, bhh1, bias0, bias1);
    k_prep_b<<<(7 * 28672 + 255) / 256, 256, 0, stream>>>(Wih0, Whh0, Wih1, Whh1, B0, B1);
    k_lstm<<<NB, 512, 0, stream>>>(x, len, rowmap, B0, B1, bias0, bias1, Wfc, bfc, out);
}

// Round 7
// 3346.880 us; speedup vs baseline: 1.2430x; 1.2430x over previous
//
#include <hip/hip_runtime.h>
#include <math.h>

typedef short bf16x8 __attribute__((ext_vector_type(8)));
typedef float f32x4  __attribute__((ext_vector_type(4)));
typedef unsigned short u16;

// Problem constants (B=4096, T=100, F=13, H=100)
#define B_  4096
#define T_  100
#define F_  13
#define NB  128    // blocks (L2-proven: full weight set resident per XCD-L2)
#define MR  32     // rows per block
#define S0  136    // A0 row stride u16: [0..100)=h0, [100..113)=x, rest 0
#define S1  232    // A1 row stride u16: [0..100)=h0n, [100..200)=h1, rest 0

// ws layout (bytes), total 651,264 (same as round 3)
#define O_HIST   0u
#define O_ROWMAP 512u
#define O_BIAS0  16896u
#define O_BIAS1  18688u
#define O_B0     20480u    // 229376 B
#define O_B1     249856u   // 401408 B -> 651264

// B-fragment layout (u16 index) — ROUND-3 PROVEN (L2-resident):
//   idx = (((kt*4+g)*7 + ct)*2 + pass)*512 + lane*8 + j
// lane elem j = W_pass[k = kt*32 + (lane>>4)*8 + j][col = g*100 + ct*16 + (lane&15)]

__device__ __forceinline__ float sigmoid_f(float v) {
    return 1.0f / (1.0f + __expf(-v));
}
__device__ __forceinline__ float tanh_f(float v) {
    float e = __expf(2.0f * v);
    return 1.0f - 2.0f / (e + 1.0f);
}
__device__ __forceinline__ void split_bf16(float v, u16& hi, u16& lo) {
    unsigned u = __float_as_uint(v);
    hi = (u16)(u >> 16);
    float rem = v - __uint_as_float(u & 0xFFFF0000u);
    unsigned r = __float_as_uint(rem);
    unsigned rnd = r + 0x7FFFu + ((r >> 16) & 1u);
    lo = (u16)(rnd >> 16);
}
__device__ __forceinline__ float bf16_to_f(u16 b) {
    return __uint_as_float(((unsigned)b) << 16);
}

// ---------------- prep kernels (round-3 proven, verbatim) ----------------
__global__ void k_hist(const int* __restrict__ len, int* __restrict__ hist) {
    int b = blockIdx.x * blockDim.x + threadIdx.x;
    if (b < B_) atomicAdd(&hist[len[b]], 1);
}
__global__ void k_scan(int* __restrict__ hist) {
    if (threadIdx.x == 0 && blockIdx.x == 0) {
        int acc = 0;
        for (int l = 0; l <= 100; ++l) { int c = hist[l]; hist[l] = acc; acc += c; }
    }
}
__global__ void k_scatter(const int* __restrict__ len, int* __restrict__ hist,
                          int* __restrict__ rowmap) {
    int b = blockIdx.x * blockDim.x + threadIdx.x;
    if (b < B_) {
        int pos = atomicAdd(&hist[len[b]], 1);
        rowmap[pos] = b;
    }
}
__global__ void k_prep_bias(const float* __restrict__ bih0, const float* __restrict__ bhh0,
                            const float* __restrict__ bih1, const float* __restrict__ bhh1,
                            float* __restrict__ bias0, float* __restrict__ bias1) {
    int idx = blockIdx.x * blockDim.x + threadIdx.x;
    if (idx < 448) {
        int g = idx / 112, cell = idx % 112;
        float v0 = 0.f, v1 = 0.f;
        if (cell < 100) {
            int row = g * 100 + cell;
            v0 = bih0[row] + bhh0[row];
            v1 = bih1[row] + bhh1[row];
        }
        bias0[idx] = v0; bias1[idx] = v1;
    }
}
__global__ void k_prep_b(const float* __restrict__ Wih0, const float* __restrict__ Whh0,
                         const float* __restrict__ Wih1, const float* __restrict__ Whh1,
                         u16* __restrict__ B0, u16* __restrict__ B1) {
    const int PER_KT = 4 * 7 * 2 * 512;  // 28672 u16 per K-tile
    int idx = blockIdx.x * blockDim.x + threadIdx.x;
    if (idx >= 7 * PER_KT) return;
    int kt = idx / PER_KT;
    int s  = idx % PER_KT;
    int g  = s / 7168;
    int s2 = s % 7168;
    int ct = s2 / 1024;
    int s3 = s2 % 1024;
    int pass = s3 / 512;
    int e  = s3 % 512;
    int lane = e >> 3, j = e & 7;
    int n = lane & 15, q = lane >> 4;
    int k = kt * 32 + q * 8 + j;
    int cell = ct * 16 + n;
    u16 hi, lo;
    {   // layer 1
        float w = 0.f;
        if (cell < 100) {
            int row = g * 100 + cell;
            if (k < 100)      w = Wih1[row * 100 + k];
            else if (k < 200) w = Whh1[row * 100 + (k - 100)];
        }
        split_bf16(w, hi, lo);
        B1[idx] = pass ? lo : hi;
    }
    if (kt < 4) {  // layer 0
        float w = 0.f;
        if (cell < 100) {
            int row = g * 100 + cell;
            if (k < 100)      w = Whh0[row * 100 + k];
            else if (k < 113) w = Wih0[row * 13 + (k - 100)];
        }
        split_bf16(w, hi, lo);
        B0[idx] = pass ? lo : hi;
    }
}

// ---------------- GEMM chunk (R3-proven addressing, loads-at-use) ----------
// bp = B + ct*1024 + lane*8 ; chunk kt gate g at +(kt*4+g)*7168 (+512 for lo)
__device__ __forceinline__ void chunkMM(const u16* __restrict__ bp, int kt,
                                        const u16* __restrict__ aH,
                                        const u16* __restrict__ aL,
                                        int stride, f32x4 (&P)[2][4]) {
    bf16x8 ah[2], al[2];
#pragma unroll
    for (int mt = 0; mt < 2; ++mt) {
        ah[mt] = *(const bf16x8*)(aH + mt * 16 * stride + kt * 32);
        al[mt] = *(const bf16x8*)(aL + mt * 16 * stride + kt * 32);
    }
#pragma unroll
    for (int g = 0; g < 4; ++g) {
        const u16* p = bp + (size_t)(kt * 4 + g) * 7168;
        bf16x8 bh = *(const bf16x8*)(p);
        bf16x8 bl = *(const bf16x8*)(p + 512);
#pragma unroll
        for (int mt = 0; mt < 2; ++mt) {
            P[mt][g] = __builtin_amdgcn_mfma_f32_16x16x32_bf16(ah[mt], bh, P[mt][g], 0, 0, 0);
            P[mt][g] = __builtin_amdgcn_mfma_f32_16x16x32_bf16(al[mt], bh, P[mt][g], 0, 0, 0);
            P[mt][g] = __builtin_amdgcn_mfma_f32_16x16x32_bf16(ah[mt], bl, P[mt][g], 0, 0, 0);
        }
    }
}

// ---------------- main persistent MFMA LSTM ----------------
// 128 blocks x 32 rows, 16 waves (4/SIMD). Waves 0..13 = (ct, kh): column-tile
// ct (16 cells, all gates, both M-tiles) x K-half kh. Each wave publishes its
// opposite-M-tile partial z to Zbuf, finalizes its own M-tile (z-sum + pointwise).
// Waves 14,15 = x prefetch. 4 barriers/step, single-buffered A state.
__global__ __launch_bounds__(1024, 4) void k_lstm(
    const float* __restrict__ x, const int* __restrict__ lengths,
    const int* __restrict__ rowmap,
    const u16* __restrict__ B0, const u16* __restrict__ B1,
    const float* __restrict__ bias0, const float* __restrict__ bias1,
    const float* __restrict__ Wfc, const float* __restrict__ bfc,
    float* __restrict__ out)
{
    __shared__ __align__(16) u16 Ah0[MR * S0];      // 8704 B
    __shared__ __align__(16) u16 Al0[MR * S0];
    __shared__ __align__(16) u16 Ah1[MR * S1];      // 14848 B
    __shared__ __align__(16) u16 Al1[MR * S1];
    __shared__ __align__(16) float Zbuf[7 * 2 * 4 * 256];   // 57344 B partial-z exchange
    __shared__ int sRow[MR], sLen[MR], sTmax;

    const int tid = threadIdx.x;
    const int wv = tid >> 6, lane = tid & 63;

    if (tid < MR) {
        int r = rowmap[blockIdx.x * MR + tid];
        sRow[tid] = r; sLen[tid] = lengths[r];
    }
    if (tid == 0) {   // same wave as the sLen writes -> in-order LDS
        int m = 0;
        for (int i = 0; i < MR; ++i) m = max(m, sLen[i]);
        sTmax = m;
    }
    {
        unsigned* p0 = (unsigned*)Ah0; unsigned* p1 = (unsigned*)Al0;
        unsigned* p2 = (unsigned*)Ah1; unsigned* p3 = (unsigned*)Al1;
        for (int i = tid; i < (MR * S0) / 2; i += 1024) { p0[i] = 0; p1[i] = 0; }
        for (int i = tid; i < (MR * S1) / 2; i += 1024) { p2[i] = 0; p3[i] = 0; }
    }
    __syncthreads();
    const int Tmax = sTmax;

    const bool isComp = (wv < 14);
    const int ct  = isComp ? (wv % 7) : 0;
    const int kh  = isComp ? (wv / 7) : 0;   // K-half this wave computes
    const int mtw = kh;                      // M-tile this wave finalizes
    const int om  = kh ^ 1;                  // M-tile partial it publishes
    const int n = lane & 15, q = lane >> 4;
    const int cell = ct * 16 + n;
    const bool cw = isComp && (cell < 100);

    float b0v[4], b1v[4], c0v[4], c1v[4];
    int   lenR[4];
    int   offA0 = 0, offA1 = 0;
    const u16* b0p = B0; const u16* b1p = B1;
    float* Zw = Zbuf; const float* Zr = Zbuf;

    // x-loader state (waves 14,15: 416 slots over 128 lanes, 4 per lane)
    float xv[4]; int xok[4] = {0, 0, 0, 0}; size_t xg[4]; int xa[4];

    if (isComp) {
#pragma unroll
        for (int g = 0; g < 4; ++g) {
            b0v[g] = bias0[g * 112 + cell];
            b1v[g] = bias1[g * 112 + cell];
        }
#pragma unroll
        for (int r = 0; r < 4; ++r) {
            lenR[r] = sLen[mtw * 16 + q * 4 + r];
            c0v[r] = 0.f; c1v[r] = 0.f;
        }
        offA0 = n * S0 + q * 8;
        offA1 = n * S1 + q * 8;
        b0p = B0 + ct * 1024 + lane * 8;
        b1p = B1 + ct * 1024 + lane * 8;
        Zw = Zbuf + ((ct * 2 + om)  * 4) * 256 + lane * 4;
        Zr = Zbuf + ((ct * 2 + mtw) * 4) * 256 + lane * 4;
    } else {
        int lidx = (wv - 14) * 64 + lane;
#pragma unroll
        for (int i = 0; i < 4; ++i) {
            int e = i * 128 + lidx;
            xok[i] = (e < MR * F_);
            int r = xok[i] ? (e / F_) : 0;
            int f = xok[i] ? (e - F_ * r) : 0;
            xg[i] = (size_t)sRow[r] * (T_ * F_) + f;
            xa[i] = r * S0 + 100 + f;
            if (xok[i]) {     // x(0); published by first in-loop barrier
                u16 hi, lo; split_bf16(x[xg[i]], hi, lo);
                Ah0[xa[i]] = hi; Al0[xa[i]] = lo;
            }
        }
    }

    for (int t = 0; t < Tmax; ++t) {
        __syncthreads();   // B1: x(t)+h0(t-1) in A0, h1(t-1) in A1 visible
        f32x4 P[2][4];
        if (isComp) {
            // ---------- layer-0 GEMM, own K-half (chunks kh? {2,3} : {0,1}) ----
#pragma unroll
            for (int mt = 0; mt < 2; ++mt)
#pragma unroll
                for (int g = 0; g < 4; ++g) P[mt][g] = (f32x4){0.f, 0.f, 0.f, 0.f};
#pragma unroll
            for (int i = 0; i < 2; ++i)
                chunkMM(b0p, (kh ? 2 : 0) + i, &Ah0[offA0], &Al0[offA0], S0, P);
#pragma unroll
            for (int g = 0; g < 4; ++g) *(f32x4*)(Zw + g * 256) = P[om][g];
        } else {
            if (t + 1 < Tmax) {
#pragma unroll
                for (int i = 0; i < 4; ++i)
                    if (xok[i]) xv[i] = x[xg[i] + (size_t)(t + 1) * F_];
            }
        }

        __syncthreads();   // B2: Zbuf(L0) ready; all A0 reads done
        if (isComp) {
            f32x4 zz[4];
#pragma unroll
            for (int g = 0; g < 4; ++g) zz[g] = P[mtw][g] + *(const f32x4*)(Zr + g * 256);
#pragma unroll
            for (int r = 0; r < 4; ++r) {
                float zi = zz[0][r] + b0v[0], zf = zz[1][r] + b0v[1];
                float zg = zz[2][r] + b0v[2], zo = zz[3][r] + b0v[3];
                float cn = sigmoid_f(zf) * c0v[r] + sigmoid_f(zi) * tanh_f(zg);
                float hn = sigmoid_f(zo) * tanh_f(cn);
                if (t < lenR[r]) {
                    c0v[r] = cn;
                    if (cw) {
                        int m = mtw * 16 + q * 4 + r;
                        u16 hi, lo; split_bf16(hn, hi, lo);
                        Ah0[m * S0 + cell] = hi; Al0[m * S0 + cell] = lo;   // h0(t)
                        Ah1[m * S1 + cell] = hi; Al1[m * S1 + cell] = lo;   // h0n(t)
                    }
                }
            }
        } else {
            if (t + 1 < Tmax) {   // x(t+1) into A0 (x-slot reads for t done at B2)
#pragma unroll
                for (int i = 0; i < 4; ++i) if (xok[i]) {
                    u16 hi, lo; split_bf16(xv[i], hi, lo);
                    Ah0[xa[i]] = hi; Al0[xa[i]] = lo;
                }
            }
        }

        __syncthreads();   // B3: h0n(t) visible; Zbuf(L0) reads done
        if (isComp) {
            // ---------- layer-1 GEMM, own K-half (chunks kh? {3..6} : {0..2}) --
#pragma unroll
            for (int mt = 0; mt < 2; ++mt)
#pragma unroll
                for (int g = 0; g < 4; ++g) P[mt][g] = (f32x4){0.f, 0.f, 0.f, 0.f};
#pragma unroll
            for (int i = 0; i < 4; ++i) {
                if (kh || i < 3)
                    chunkMM(b1p, kh ? (3 + i) : i, &Ah1[offA1], &Al1[offA1], S1, P);
            }
#pragma unroll
            for (int g = 0; g < 4; ++g) *(f32x4*)(Zw + g * 256) = P[om][g];
        }

        __syncthreads();   // B4: Zbuf(L1) ready; all A1 reads done
        if (isComp) {
            f32x4 zz[4];
#pragma unroll
            for (int g = 0; g < 4; ++g) zz[g] = P[mtw][g] + *(const f32x4*)(Zr + g * 256);
#pragma unroll
            for (int r = 0; r < 4; ++r) {
                float zi = zz[0][r] + b1v[0], zf = zz[1][r] + b1v[1];
                float zg = zz[2][r] + b1v[2], zo = zz[3][r] + b1v[3];
                float cn = sigmoid_f(zf) * c1v[r] + sigmoid_f(zi) * tanh_f(zg);
                float hn = sigmoid_f(zo) * tanh_f(cn);
                if (t < lenR[r]) {
                    c1v[r] = cn;
                    if (cw) {
                        int m = mtw * 16 + q * 4 + r;
                        u16 hi, lo; split_bf16(hn, hi, lo);
                        Ah1[m * S1 + 100 + cell] = hi;   // h1(t), frozen after len-1
                        Al1[m * S1 + 100 + cell] = lo;
                    }
                }
            }
        }
    }
    __syncthreads();

    // out[b] = W_fc . h1(len-1) + b_fc
    if (tid < MR) {
        float s = bfc[0];
        for (int j = 0; j < 100; ++j)
            s = fmaf(Wfc[j], bf16_to_f(Ah1[tid * S1 + 100 + j]) +
                             bf16_to_f(Al1[tid * S1 + 100 + j]), s);
        out[sRow[tid]] = s;
    }
}

// ---------------- launch ----------------
extern "C" void kernel_launch(void* const* d_in, const int* in_sizes, int n_in,
                              void* d_out, int out_size, void* d_ws, size_t ws_size,
                              hipStream_t stream) {
    const float* x    = (const float*)d_in[0];
    const int*   len  = (const int*)d_in[1];
    const float* Wih0 = (const float*)d_in[2];
    const float* Whh0 = (const float*)d_in[3];
    const float* bih0 = (const float*)d_in[4];
    const float* bhh0 = (const float*)d_in[5];
    const float* Wih1 = (const float*)d_in[6];
    const float* Whh1 = (const float*)d_in[7];
    const float* bih1 = (const float*)d_in[8];
    const float* bhh1 = (const float*)d_in[9];
    const float* Wfc  = (const float*)d_in[10];
    const float* bfc  = (const float*)d_in[11];
    float* out = (float*)d_out;

    char* ws = (char*)d_ws;   // uses 651,264 bytes
    int*   hist   = (int*)(ws + O_HIST);
    int*   rowmap = (int*)(ws + O_ROWMAP);
    float* bias0  = (float*)(ws + O_BIAS0);
    float* bias1  = (float*)(ws + O_BIAS1);
    u16*   B0     = (u16*)(ws + O_B0);
    u16*   B1     = (u16*)(ws + O_B1);

    (void)hipMemsetAsync(hist, 0, 512, stream);
    k_hist<<<16, 256, 0, stream>>>(len, hist);
    k_scan<<<1, 64, 0, stream>>>(hist);
    k_scatter<<<16, 256, 0, stream>>>(len, hist, rowmap);
    k_prep_bias<<<2, 256, 0, stream>>>(bih0, bhh0, bih1, bhh1, bias0, bias1);
    k_prep_b<<<(7 * 28672 + 255) / 256, 256, 0, stream>>>(Wih0, Whh0, Wih1, Whh1, B0, B1);
    k_lstm<<<NB, 1024, 0, stream>>>(x, len, rowmap, B0, B1, bias0, bias1, Wfc, bfc, out);
}

// Round 8
// 3315.109 us; speedup vs baseline: 1.2549x; 1.0096x over previous
//
#include <hip/hip_runtime.h>
#include <math.h>

typedef short bf16x8 __attribute__((ext_vector_type(8)));
typedef float f32x4  __attribute__((ext_vector_type(4)));
typedef unsigned short u16;

// Problem constants (B=4096, T=100, F=13, H=100)
#define B_  4096
#define T_  100
#define F_  13
#define NB  128    // blocks (L2-proven: full weight set resident per XCD-L2)
#define MR  32     // rows per block
#define S0  136    // A0 row stride u16: [0..100)=h0, [100..113)=x, rest 0
#define S1  232    // A1 row stride u16: [0..100)=h0n, [100..200)=h1, rest 0

// ws layout (bytes), total 651,264 (same as round 3)
#define O_HIST   0u
#define O_ROWMAP 512u
#define O_BIAS0  16896u
#define O_BIAS1  18688u
#define O_B0     20480u    // 229376 B
#define O_B1     249856u   // 401408 B -> 651264

// B-fragment layout (u16 index) — ROUND-3 PROVEN (L2-resident):
//   idx = (((kt*4+g)*7 + ct)*2 + pass)*512 + lane*8 + j
// lane elem j = W_pass[k = kt*32 + (lane>>4)*8 + j][col = g*100 + ct*16 + (lane&15)]

__device__ __forceinline__ float sigmoid_f(float v) {
    return 1.0f / (1.0f + __expf(-v));
}
__device__ __forceinline__ float tanh_f(float v) {
    float e = __expf(2.0f * v);
    return 1.0f - 2.0f / (e + 1.0f);
}
__device__ __forceinline__ void split_bf16(float v, u16& hi, u16& lo) {
    unsigned u = __float_as_uint(v);
    hi = (u16)(u >> 16);
    float rem = v - __uint_as_float(u & 0xFFFF0000u);
    unsigned r = __float_as_uint(rem);
    unsigned rnd = r + 0x7FFFu + ((r >> 16) & 1u);
    lo = (u16)(rnd >> 16);
}
__device__ __forceinline__ float bf16_to_f(u16 b) {
    return __uint_as_float(((unsigned)b) << 16);
}

// ---------------- prep kernels (round-3 proven, verbatim) ----------------
__global__ void k_hist(const int* __restrict__ len, int* __restrict__ hist) {
    int b = blockIdx.x * blockDim.x + threadIdx.x;
    if (b < B_) atomicAdd(&hist[len[b]], 1);
}
__global__ void k_scan(int* __restrict__ hist) {
    if (threadIdx.x == 0 && blockIdx.x == 0) {
        int acc = 0;
        for (int l = 0; l <= 100; ++l) { int c = hist[l]; hist[l] = acc; acc += c; }
    }
}
__global__ void k_scatter(const int* __restrict__ len, int* __restrict__ hist,
                          int* __restrict__ rowmap) {
    int b = blockIdx.x * blockDim.x + threadIdx.x;
    if (b < B_) {
        int pos = atomicAdd(&hist[len[b]], 1);
        rowmap[pos] = b;
    }
}
__global__ void k_prep_bias(const float* __restrict__ bih0, const float* __restrict__ bhh0,
                            const float* __restrict__ bih1, const float* __restrict__ bhh1,
                            float* __restrict__ bias0, float* __restrict__ bias1) {
    int idx = blockIdx.x * blockDim.x + threadIdx.x;
    if (idx < 448) {
        int g = idx / 112, cell = idx % 112;
        float v0 = 0.f, v1 = 0.f;
        if (cell < 100) {
            int row = g * 100 + cell;
            v0 = bih0[row] + bhh0[row];
            v1 = bih1[row] + bhh1[row];
        }
        bias0[idx] = v0; bias1[idx] = v1;
    }
}
__global__ void k_prep_b(const float* __restrict__ Wih0, const float* __restrict__ Whh0,
                         const float* __restrict__ Wih1, const float* __restrict__ Whh1,
                         u16* __restrict__ B0, u16* __restrict__ B1) {
    const int PER_KT = 4 * 7 * 2 * 512;  // 28672 u16 per K-tile
    int idx = blockIdx.x * blockDim.x + threadIdx.x;
    if (idx >= 7 * PER_KT) return;
    int kt = idx / PER_KT;
    int s  = idx % PER_KT;
    int g  = s / 7168;
    int s2 = s % 7168;
    int ct = s2 / 1024;
    int s3 = s2 % 1024;
    int pass = s3 / 512;
    int e  = s3 % 512;
    int lane = e >> 3, j = e & 7;
    int n = lane & 15, q = lane >> 4;
    int k = kt * 32 + q * 8 + j;
    int cell = ct * 16 + n;
    u16 hi, lo;
    {   // layer 1
        float w = 0.f;
        if (cell < 100) {
            int row = g * 100 + cell;
            if (k < 100)      w = Wih1[row * 100 + k];
            else if (k < 200) w = Whh1[row * 100 + (k - 100)];
        }
        split_bf16(w, hi, lo);
        B1[idx] = pass ? lo : hi;
    }
    if (kt < 4) {  // layer 0
        float w = 0.f;
        if (cell < 100) {
            int row = g * 100 + cell;
            if (k < 100)      w = Whh0[row * 100 + k];
            else if (k < 113) w = Wih0[row * 13 + (k - 100)];
        }
        split_bf16(w, hi, lo);
        B0[idx] = pass ? lo : hi;
    }
}

// ---------------- GEMM chunk (R3-proven addressing, loads-at-use) ----------
// bp = B + ct*1024 + lane*8 ; chunk kt gate g at +(kt*4+g)*7168 (+512 for lo)
__device__ __forceinline__ void chunkMM(const u16* __restrict__ bp, int kt,
                                        const u16* __restrict__ aH,
                                        const u16* __restrict__ aL,
                                        int stride, f32x4 (&P)[2][4]) {
    bf16x8 ah[2], al[2];
#pragma unroll
    for (int mt = 0; mt < 2; ++mt) {
        ah[mt] = *(const bf16x8*)(aH + mt * 16 * stride + kt * 32);
        al[mt] = *(const bf16x8*)(aL + mt * 16 * stride + kt * 32);
    }
#pragma unroll
    for (int g = 0; g < 4; ++g) {
        const u16* p = bp + (size_t)(kt * 4 + g) * 7168;
        bf16x8 bh = *(const bf16x8*)(p);
        bf16x8 bl = *(const bf16x8*)(p + 512);
#pragma unroll
        for (int mt = 0; mt < 2; ++mt) {
            P[mt][g] = __builtin_amdgcn_mfma_f32_16x16x32_bf16(ah[mt], bh, P[mt][g], 0, 0, 0);
            P[mt][g] = __builtin_amdgcn_mfma_f32_16x16x32_bf16(al[mt], bh, P[mt][g], 0, 0, 0);
            P[mt][g] = __builtin_amdgcn_mfma_f32_16x16x32_bf16(ah[mt], bl, P[mt][g], 0, 0, 0);
        }
    }
}

// ---------------- main persistent MFMA LSTM ----------------
// 128 blocks x 32 rows, 16 waves (4/SIMD). Waves 0..13 = (ct, kh): column-tile
// ct (16 cells, all gates, both M-tiles) x K-half kh. Each wave publishes its
// opposite-M-tile partial z to Zbuf, finalizes its own M-tile (z-sum + pointwise).
// Waves 14,15 = x prefetch. 4 barriers/step, single-buffered A state.
// __launch_bounds__(1024, 1): R7's (1024,4) made the compiler target 8 waves/EU
// -> 64 VGPRs -> 2.3 GB/dispatch of scratch spills (the entire regression).
// (1024,1) guarantees a >=128-VGPR budget under either 2nd-arg semantics.
__global__ __launch_bounds__(1024, 1) void k_lstm(
    const float* __restrict__ x, const int* __restrict__ lengths,
    const int* __restrict__ rowmap,
    const u16* __restrict__ B0, const u16* __restrict__ B1,
    const float* __restrict__ bias0, const float* __restrict__ bias1,
    const float* __restrict__ Wfc, const float* __restrict__ bfc,
    float* __restrict__ out)
{
    __shared__ __align__(16) u16 Ah0[MR * S0];      // 8704 B
    __shared__ __align__(16) u16 Al0[MR * S0];
    __shared__ __align__(16) u16 Ah1[MR * S1];      // 14848 B
    __shared__ __align__(16) u16 Al1[MR * S1];
    __shared__ __align__(16) float Zbuf[7 * 2 * 4 * 256];   // 57344 B partial-z exchange
    __shared__ int sRow[MR], sLen[MR], sTmax;

    const int tid = threadIdx.x;
    const int wv = tid >> 6, lane = tid & 63;

    if (tid < MR) {
        int r = rowmap[blockIdx.x * MR + tid];
        sRow[tid] = r; sLen[tid] = lengths[r];
    }
    if (tid == 0) {   // same wave as the sLen writes -> in-order LDS
        int m = 0;
        for (int i = 0; i < MR; ++i) m = max(m, sLen[i]);
        sTmax = m;
    }
    {
        unsigned* p0 = (unsigned*)Ah0; unsigned* p1 = (unsigned*)Al0;
        unsigned* p2 = (unsigned*)Ah1; unsigned* p3 = (unsigned*)Al1;
        for (int i = tid; i < (MR * S0) / 2; i += 1024) { p0[i] = 0; p1[i] = 0; }
        for (int i = tid; i < (MR * S1) / 2; i += 1024) { p2[i] = 0; p3[i] = 0; }
    }
    __syncthreads();
    const int Tmax = sTmax;

    const bool isComp = (wv < 14);
    const int ct  = isComp ? (wv % 7) : 0;
    const int kh  = isComp ? (wv / 7) : 0;   // K-half this wave computes
    const int mtw = kh;                      // M-tile this wave finalizes
    const int om  = kh ^ 1;                  // M-tile partial it publishes
    const int n = lane & 15, q = lane >> 4;
    const int cell = ct * 16 + n;
    const bool cw = isComp && (cell < 100);

    float b0v[4], b1v[4], c0v[4], c1v[4];
    int   lenR[4];
    int   offA0 = 0, offA1 = 0;
    const u16* b0p = B0; const u16* b1p = B1;
    float* Zw = Zbuf; const float* Zr = Zbuf;

    // x-loader state (waves 14,15: 416 slots over 128 lanes, 4 per lane)
    float xv[4]; int xok[4] = {0, 0, 0, 0}; size_t xg[4]; int xa[4];

    if (isComp) {
#pragma unroll
        for (int g = 0; g < 4; ++g) {
            b0v[g] = bias0[g * 112 + cell];
            b1v[g] = bias1[g * 112 + cell];
        }
#pragma unroll
        for (int r = 0; r < 4; ++r) {
            lenR[r] = sLen[mtw * 16 + q * 4 + r];
            c0v[r] = 0.f; c1v[r] = 0.f;
        }
        offA0 = n * S0 + q * 8;
        offA1 = n * S1 + q * 8;
        b0p = B0 + ct * 1024 + lane * 8;
        b1p = B1 + ct * 1024 + lane * 8;
        Zw = Zbuf + ((ct * 2 + om)  * 4) * 256 + lane * 4;
        Zr = Zbuf + ((ct * 2 + mtw) * 4) * 256 + lane * 4;
    } else {
        int lidx = (wv - 14) * 64 + lane;
#pragma unroll
        for (int i = 0; i < 4; ++i) {
            int e = i * 128 + lidx;
            xok[i] = (e < MR * F_);
            int r = xok[i] ? (e / F_) : 0;
            int f = xok[i] ? (e - F_ * r) : 0;
            xg[i] = (size_t)sRow[r] * (T_ * F_) + f;
            xa[i] = r * S0 + 100 + f;
            if (xok[i]) {     // x(0); published by first in-loop barrier
                u16 hi, lo; split_bf16(x[xg[i]], hi, lo);
                Ah0[xa[i]] = hi; Al0[xa[i]] = lo;
            }
        }
    }

    for (int t = 0; t < Tmax; ++t) {
        __syncthreads();   // B1: x(t)+h0(t-1) in A0, h1(t-1) in A1 visible
        f32x4 P[2][4];
        if (isComp) {
            // ---------- layer-0 GEMM, own K-half (chunks kh? {2,3} : {0,1}) ----
#pragma unroll
            for (int mt = 0; mt < 2; ++mt)
#pragma unroll
                for (int g = 0; g < 4; ++g) P[mt][g] = (f32x4){0.f, 0.f, 0.f, 0.f};
#pragma unroll
            for (int i = 0; i < 2; ++i)
                chunkMM(b0p, (kh ? 2 : 0) + i, &Ah0[offA0], &Al0[offA0], S0, P);
#pragma unroll
            for (int g = 0; g < 4; ++g) *(f32x4*)(Zw + g * 256) = P[om][g];
        } else {
            if (t + 1 < Tmax) {
#pragma unroll
                for (int i = 0; i < 4; ++i)
                    if (xok[i]) xv[i] = x[xg[i] + (size_t)(t + 1) * F_];
            }
        }

        __syncthreads();   // B2: Zbuf(L0) ready; all A0 reads done
        if (isComp) {
            f32x4 zz[4];
#pragma unroll
            for (int g = 0; g < 4; ++g) zz[g] = P[mtw][g] + *(const f32x4*)(Zr + g * 256);
#pragma unroll
            for (int r = 0; r < 4; ++r) {
                float zi = zz[0][r] + b0v[0], zf = zz[1][r] + b0v[1];
                float zg = zz[2][r] + b0v[2], zo = zz[3][r] + b0v[3];
                float cn = sigmoid_f(zf) * c0v[r] + sigmoid_f(zi) * tanh_f(zg);
                float hn = sigmoid_f(zo) * tanh_f(cn);
                if (t < lenR[r]) {
                    c0v[r] = cn;
                    if (cw) {
                        int m = mtw * 16 + q * 4 + r;
                        u16 hi, lo; split_bf16(hn, hi, lo);
                        Ah0[m * S0 + cell] = hi; Al0[m * S0 + cell] = lo;   // h0(t)
                        Ah1[m * S1 + cell] = hi; Al1[m * S1 + cell] = lo;   // h0n(t)
                    }
                }
            }
        } else {
            if (t + 1 < Tmax) {   // x(t+1) into A0 (x-slot reads for t done at B2)
#pragma unroll
                for (int i = 0; i < 4; ++i) if (xok[i]) {
                    u16 hi, lo; split_bf16(xv[i], hi, lo);
                    Ah0[xa[i]] = hi; Al0[xa[i]] = lo;
                }
            }
        }

        __syncthreads();   // B3: h0n(t) visible; Zbuf(L0) reads done
        if (isComp) {
            // ---------- layer-1 GEMM, own K-half (chunks kh? {3..6} : {0..2}) --
#pragma unroll
            for (int mt = 0; mt < 2; ++mt)
#pragma unroll
                for (int g = 0; g < 4; ++g) P[mt][g] = (f32x4){0.f, 0.f, 0.f, 0.f};
#pragma unroll
            for (int i = 0; i < 4; ++i) {
                if (kh || i < 3)
                    chunkMM(b1p, kh ? (3 + i) : i, &Ah1[offA1], &Al1[offA1], S1, P);
            }
#pragma unroll
            for (int g = 0; g < 4; ++g) *(f32x4*)(Zw + g * 256) = P[om][g];
        }

        __syncthreads();   // B4: Zbuf(L1) ready; all A1 reads done
        if (isComp) {
            f32x4 zz[4];
#pragma unroll
            for (int g = 0; g < 4; ++g) zz[g] = P[mtw][g] + *(const f32x4*)(Zr + g * 256);
#pragma unroll
            for (int r = 0; r < 4; ++r) {
                float zi = zz[0][r] + b1v[0], zf = zz[1][r] + b1v[1];
                float zg = zz[2][r] + b1v[2], zo = zz[3][r] + b1v[3];
                float cn = sigmoid_f(zf) * c1v[r] + sigmoid_f(zi) * tanh_f(zg);
                float hn = sigmoid_f(zo) * tanh_f(cn);
                if (t < lenR[r]) {
                    c1v[r] = cn;
                    if (cw) {
                        int m = mtw * 16 + q * 4 + r;
                        u16 hi, lo; split_bf16(hn, hi, lo);
                        Ah1[m * S1 + 100 + cell] = hi;   // h1(t), frozen after len-1
                        Al1[m * S1 + 100 + cell] = lo;
                    }
                }
            }
        }
    }
    __syncthreads();

    // out[b] = W_fc . h1(len-1) + b_fc
    if (tid < MR) {
        float s = bfc[0];
        for (int j = 0; j < 100; ++j)
            s = fmaf(Wfc[j], bf16_to_f(Ah1[tid * S1 + 100 + j]) +
                             bf16_to_f(Al1[tid * S1 + 100 + j]), s);
        out[sRow[tid]] = s;
    }
}

// ---------------- launch ----------------
extern "C" void kernel_launch(void* const* d_in, const int* in_sizes, int n_in,
                              void* d_out, int out_size, void* d_ws, size_t ws_size,
                              hipStream_t stream) {
    const float* x    = (const float*)d_in[0];
    const int*   len  = (const int*)d_in[1];
    const float* Wih0 = (const float*)d_in[2];
    const float* Whh0 = (const float*)d_in[3];
    const float* bih0 = (const float*)d_in[4];
    const float* bhh0 = (const float*)d_in[5];
    const float* Wih1 = (const float*)d_in[6];
    const float* Whh1 = (const float*)d_in[7];
    const float* bih1 = (const float*)d_in[8];
    const float* bhh1 = (const float*)d_in[9];
    const float* Wfc  = (const float*)d_in[10];
    const float* bfc  = (const float*)d_in[11];
    float* out = (float*)d_out;

    char* ws = (char*)d_ws;   // uses 651,264 bytes
    int*   hist   = (int*)(ws + O_HIST);
    int*   rowmap = (int*)(ws + O_ROWMAP);
    float* bias0  = (float*)(ws + O_BIAS0);
    float* bias1  = (float*)(ws + O_BIAS1);
    u16*   B0     = (u16*)(ws + O_B0);
    u16*   B1     = (u16*)(ws + O_B1);

    (void)hipMemsetAsync(hist, 0, 512, stream);
    k_hist<<<16, 256, 0, stream>>>(len, hist);
    k_scan<<<1, 64, 0, stream>>>(hist);
    k_scatter<<<16, 256, 0, stream>>>(len, hist, rowmap);
    k_prep_bias<<<2, 256, 0, stream>>>(bih0, bhh0, bih1, bhh1, bias0, bias1);
    k_prep_b<<<(7 * 28672 + 255) / 256, 256, 0, stream>>>(Wih0, Whh0, Wih1, Whh1, B0, B1);
    k_lstm<<<NB, 1024, 0, stream>>>(x, len, rowmap, B0, B1, bias0, bias1, Wfc, bfc, out);
}